// Round 2
// baseline (283.838 us; speedup 1.0000x reference)
//
#include <hip/hip_runtime.h>

typedef unsigned short u16;
typedef __bf16 bf16x8 __attribute__((ext_vector_type(8)));
typedef float f32x4 __attribute__((ext_vector_type(4)));

#define B_ 4
#define L_ 2048
#define LOG2E 1.44269504088896340736f
#define HSTRIDE ((size_t)L_ * 64)   // one (b,t,h) plane: 2048*64 elements

// ---------- helpers ----------
__device__ __forceinline__ u16 f2bf(float f) {
    unsigned u = __float_as_uint(f);
    u += 0x7fff + ((u >> 16) & 1);   // RNE
    return (u16)(u >> 16);
}

__device__ __forceinline__ f32x4 mfma16(bf16x8 a, bf16x8 b, f32x4 c) {
    return __builtin_amdgcn_mfma_f32_16x16x32_bf16(a, b, c, 0, 0, 0);
}

// async global->LDS, 16B per lane; LDS dest is wave-uniform base + lane*16
__device__ __forceinline__ void async16(const u16* g, u16* l) {
    __builtin_amdgcn_global_load_lds(
        (const __attribute__((address_space(1))) u16*)g,
        (__attribute__((address_space(3))) u16*)l, 16, 0, 0);
}

// ---------- kernel 0a: fp32 -> bf16 convert ----------
__global__ __launch_bounds__(256) void convert_f32_bf16(const float* __restrict__ in,
                                                        u16* __restrict__ out, int n) {
    int i = (blockIdx.x * 256 + threadIdx.x) * 4;
    if (i < n) {
        float4 f = *(const float4*)(in + i);
        ushort4 r;
        r.x = f2bf(f.x); r.y = f2bf(f.y); r.z = f2bf(f.z); r.w = f2bf(f.w);
        *(ushort4*)(out + i) = r;
    }
}

// ---------- kernel 0b: x[b][i][l] fp32 -> xbt[b][l][i] bf16 (64x64 LDS tiles) ----------
__global__ __launch_bounds__(256) void transpose_x(const float* __restrict__ x,
                                                   u16* __restrict__ xbt) {
    __shared__ u16 T[64][66];
    int b  = blockIdx.z;
    int i0 = blockIdx.y * 64;   // DIM tile (512/64 = 8)
    int l0 = blockIdx.x * 64;   // L tile  (2048/64 = 32)
    int t  = threadIdx.x;
    int c  = t & 63, r4 = t >> 6;
    const float* xb = x + ((size_t)b * 512 + i0) * 2048 + l0;
#pragma unroll
    for (int r = r4; r < 64; r += 4) T[r][c] = f2bf(xb[(size_t)r * 2048 + c]);
    __syncthreads();
    u16* ob = xbt + ((size_t)b * 2048 + l0) * 512 + i0;
#pragma unroll
    for (int r = r4; r < 64; r += 4) ob[(size_t)r * 512 + c] = T[c][r];
}

// ---------- kernel 1: QKV GEMM  qkv[b,o,l] = sum_i w[o,i] x[b,i,l] ----------
// m = l (128), n = o (128), K = 512, BK = 64.  A = xbt[b][l][i], B = w[o][i].
// Q,K stored [b][t][h][l][c] (q scaled by 0.125); V stored transposed [b][2][h][c][l].
__global__ __launch_bounds__(256, 2) void qkv_gemm(const u16* __restrict__ xbt,
                                                   const u16* __restrict__ wq,
                                                   u16* __restrict__ qkv) {
    __shared__ u16 smem[16896];          // As[0:8192], Bs[8192:16384]; V-transpose reuses all
    u16* As = smem;
    u16* Bs = smem + 8192;
    int b  = blockIdx.z;
    int m0 = blockIdx.x * 128;           // l
    int n0 = blockIdx.y * 128;           // o (0..1535, 128-aligned -> t uniform per block)
    int tid = threadIdx.x;
    int lane = tid & 63, wid = tid >> 6;
    int quad = lane >> 4, n15 = lane & 15;
    const u16* Abase = xbt + ((size_t)b * L_ + m0) * 512;
    const u16* Bbase = wq + (size_t)n0 * 512;
    int mw = (wid & 1) * 64, nw = (wid >> 1) * 64;
    f32x4 acc[4][4] = {};
    for (int k0 = 0; k0 < 512; k0 += 64) {
        __syncthreads();
#pragma unroll
        for (int c = 0; c < 4; ++c) {
            int off = wid * 2048 + c * 512 + lane * 8;
            int row = off >> 6, col = off & 63;
            async16(Abase + (size_t)row * 512 + k0 + col, As + wid * 2048 + c * 512);
            async16(Bbase + (size_t)row * 512 + k0 + col, Bs + wid * 2048 + c * 512);
        }
        __syncthreads();
#pragma unroll
        for (int ks = 0; ks < 2; ++ks) {
            bf16x8 af[4], bfr[4];
#pragma unroll
            for (int i = 0; i < 4; ++i)
                af[i] = *(const bf16x8*)&As[(mw + i * 16 + n15) * 64 + ks * 32 + quad * 8];
#pragma unroll
            for (int j = 0; j < 4; ++j)
                bfr[j] = *(const bf16x8*)&Bs[(nw + j * 16 + n15) * 64 + ks * 32 + quad * 8];
#pragma unroll
            for (int i = 0; i < 4; ++i)
#pragma unroll
                for (int j = 0; j < 4; ++j)
                    acc[i][j] = mfma16(af[i], bfr[j], acc[i][j]);
        }
    }
    if (n0 < 1024) {
        // Q or K: direct store, row=l, col=o -> lanes are c-consecutive
#pragma unroll
        for (int i = 0; i < 4; ++i) {
#pragma unroll
            for (int j = 0; j < 4; ++j) {
                int o = n0 + nw + j * 16 + n15;
                int t = o >> 9, h = (o >> 6) & 7, cc = o & 63;
                float sc = (t == 0) ? 0.125f : 1.0f;   // SCALE = 64^-0.5 folded into Q
                u16* dst = qkv + (((size_t)b * 3 + t) * 8 + h) * HSTRIDE + cc;
#pragma unroll
                for (int r = 0; r < 4; ++r) {
                    int l = m0 + mw + i * 16 + quad * 4 + r;
                    dst[(size_t)l * 64] = f2bf(acc[i][j][r] * sc);   // FIX: apply sc
                }
            }
        }
    } else {
        // V: transpose through LDS, store [b][2][h][c][l] coalesced over l
        __syncthreads();
        u16* T = smem;   // [o_loc(128)][stride 132]
#pragma unroll
        for (int i = 0; i < 4; ++i)
#pragma unroll
            for (int j = 0; j < 4; ++j)
#pragma unroll
                for (int r = 0; r < 4; ++r)
                    T[(nw + j * 16 + n15) * 132 + (mw + i * 16 + quad * 4 + r)] =
                        f2bf(acc[i][j][r]);
        __syncthreads();
        int h0 = (n0 - 1024) >> 6;
        u16* Vt = qkv + ((size_t)b * 3 + 2) * 8 * HSTRIDE;
#pragma unroll
        for (int c8 = 0; c8 < 8; ++c8) {
            int off = c8 * 2048 + tid * 8;
            int cfull = off >> 7, l = off & 127;
            int h = h0 + (cfull >> 6), cc = cfull & 63;
            ushort4 lo = *(const ushort4*)&T[cfull * 132 + l];
            ushort4 hi = *(const ushort4*)&T[cfull * 132 + l + 4];
            ushort4* dst = (ushort4*)(Vt + (size_t)h * HSTRIDE + (size_t)cc * L_ + m0 + l);
            dst[0] = lo; dst[1] = hi;
        }
    }
}

// ---------- kernel 2: flash attention, one block = (b,h) x 128 q-rows ----------
__global__ __launch_bounds__(256, 2) void attn_kernel(const u16* __restrict__ qkv,
                                                      u16* __restrict__ o2) {
    __shared__ u16 Ps[128 * 136];        // per-wave-private 32-row slices: no barriers
    int bh = blockIdx.y;
    int b = bh >> 3, h = bh & 7;
    int q0 = blockIdx.x * 128;
    int tid = threadIdx.x, lane = tid & 63, wid = tid >> 6;
    int quad = lane >> 4, n15 = lane & 15;
    const u16* Qp = qkv + (((size_t)b * 3 + 0) * 8 + h) * HSTRIDE;   // [l][c]
    const u16* Kp = qkv + (((size_t)b * 3 + 1) * 8 + h) * HSTRIDE;   // [l][c]
    const u16* Vt = qkv + (((size_t)b * 3 + 2) * 8 + h) * HSTRIDE;   // [c][l]
    int mw = wid * 32;
    bf16x8 aq[2][2];
#pragma unroll
    for (int mf = 0; mf < 2; ++mf)
#pragma unroll
        for (int ks = 0; ks < 2; ++ks)
            aq[mf][ks] = *(const bf16x8*)
                &Qp[(size_t)(q0 + mw + mf * 16 + n15) * 64 + ks * 32 + quad * 8];
    f32x4 oacc[2][4] = {};
    float mrun[2][4], lrun[2][4];
#pragma unroll
    for (int mf = 0; mf < 2; ++mf)
#pragma unroll
        for (int r = 0; r < 4; ++r) { mrun[mf][r] = -3.0e38f; lrun[mf][r] = 0.f; }

    for (int kt = 0; kt < 16; ++kt) {
        int kl0 = kt * 128;
        // S = Q K^T  (K B-fragments straight from global; tiles are L1/L2 resident)
        f32x4 sacc[2][8] = {};
#pragma unroll
        for (int nf = 0; nf < 8; ++nf) {
#pragma unroll
            for (int ks = 0; ks < 2; ++ks) {
                bf16x8 bk = *(const bf16x8*)
                    &Kp[(size_t)(kl0 + nf * 16 + n15) * 64 + ks * 32 + quad * 8];
                sacc[0][nf] = mfma16(aq[0][ks], bk, sacc[0][nf]);
                sacc[1][nf] = mfma16(aq[1][ks], bk, sacc[1][nf]);
            }
        }
        // online softmax in exp2 domain
#pragma unroll
        for (int mf = 0; mf < 2; ++mf) {
            float al[4];
#pragma unroll
            for (int r = 0; r < 4; ++r) {
                float v = sacc[mf][0][r];
#pragma unroll
                for (int nf = 1; nf < 8; ++nf) v = fmaxf(v, sacc[mf][nf][r]);
                v *= LOG2E;
                v = fmaxf(v, __shfl_xor(v, 1, 64));
                v = fmaxf(v, __shfl_xor(v, 2, 64));
                v = fmaxf(v, __shfl_xor(v, 4, 64));
                v = fmaxf(v, __shfl_xor(v, 8, 64));
                float mnew = fmaxf(mrun[mf][r], v);
                al[r] = __builtin_amdgcn_exp2f(mrun[mf][r] - mnew);
                mrun[mf][r] = mnew;
                float rs = 0.f;
#pragma unroll
                for (int nf = 0; nf < 8; ++nf) {
                    float p = __builtin_amdgcn_exp2f(sacc[mf][nf][r] * LOG2E - mnew);
                    sacc[mf][nf][r] = p;
                    rs += p;
                }
                rs += __shfl_xor(rs, 1, 64);
                rs += __shfl_xor(rs, 2, 64);
                rs += __shfl_xor(rs, 4, 64);
                rs += __shfl_xor(rs, 8, 64);
                lrun[mf][r] = lrun[mf][r] * al[r] + rs;
            }
#pragma unroll
            for (int nf2 = 0; nf2 < 4; ++nf2)
#pragma unroll
                for (int r = 0; r < 4; ++r) oacc[mf][nf2][r] *= al[r];
            // P -> LDS (C-layout -> A-layout roundtrip, own rows only)
#pragma unroll
            for (int nf = 0; nf < 8; ++nf)
#pragma unroll
                for (int r = 0; r < 4; ++r)
                    Ps[(mw + mf * 16 + quad * 4 + r) * 136 + nf * 16 + n15] =
                        f2bf(sacc[mf][nf][r]);
        }
        // O += P V   (V B-fragments straight from global [c][l] layout)
#pragma unroll
        for (int ks2 = 0; ks2 < 4; ++ks2) {
            bf16x8 pa0 = *(const bf16x8*)&Ps[(mw + n15) * 136 + ks2 * 32 + quad * 8];
            bf16x8 pa1 = *(const bf16x8*)&Ps[(mw + 16 + n15) * 136 + ks2 * 32 + quad * 8];
#pragma unroll
            for (int nf2 = 0; nf2 < 4; ++nf2) {
                bf16x8 vb = *(const bf16x8*)
                    &Vt[(size_t)(nf2 * 16 + n15) * L_ + kl0 + ks2 * 32 + quad * 8];
                oacc[0][nf2] = mfma16(pa0, vb, oacc[0][nf2]);
                oacc[1][nf2] = mfma16(pa1, vb, oacc[1][nf2]);
            }
        }
    }
    // epilogue: normalize, store o2[b][l][h*64+c]
#pragma unroll
    for (int mf = 0; mf < 2; ++mf)
#pragma unroll
        for (int r = 0; r < 4; ++r) {
            float inv = 1.0f / lrun[mf][r];
            int l = q0 + mw + mf * 16 + quad * 4 + r;
#pragma unroll
            for (int nf2 = 0; nf2 < 4; ++nf2) {
                int cc = nf2 * 16 + n15;
                o2[((size_t)b * L_ + l) * 512 + h * 64 + cc] = f2bf(oacc[mf][nf2][r] * inv);
            }
        }
}

// ---------- kernel 3: out GEMM  out[b,o,l] = sum_i w_out[o,i] o2[b,l,i] + b_out[o] ----------
__global__ __launch_bounds__(256, 2) void out_gemm(const u16* __restrict__ wo,
                                                   const u16* __restrict__ o2,
                                                   const float* __restrict__ bout,
                                                   float* __restrict__ out) {
    __shared__ u16 As[8192], Bs[8192];
    int b  = blockIdx.z;
    int m0 = blockIdx.y * 128;   // o
    int n0 = blockIdx.x * 128;   // l
    int tid = threadIdx.x, lane = tid & 63, wid = tid >> 6;
    int quad = lane >> 4, n15 = lane & 15;
    const u16* Abase = wo + (size_t)m0 * 512;
    const u16* Bbase = o2 + ((size_t)b * L_ + n0) * 512;
    int mw = (wid & 1) * 64, nw = (wid >> 1) * 64;
    f32x4 acc[4][4] = {};
    for (int k0 = 0; k0 < 512; k0 += 64) {
        __syncthreads();
#pragma unroll
        for (int c = 0; c < 4; ++c) {
            int off = wid * 2048 + c * 512 + lane * 8;
            int row = off >> 6, col = off & 63;
            async16(Abase + (size_t)row * 512 + k0 + col, As + wid * 2048 + c * 512);
            async16(Bbase + (size_t)row * 512 + k0 + col, Bs + wid * 2048 + c * 512);
        }
        __syncthreads();
#pragma unroll
        for (int ks = 0; ks < 2; ++ks) {
            bf16x8 af[4], bfr[4];
#pragma unroll
            for (int i = 0; i < 4; ++i)
                af[i] = *(const bf16x8*)&As[(mw + i * 16 + n15) * 64 + ks * 32 + quad * 8];
#pragma unroll
            for (int j = 0; j < 4; ++j)
                bfr[j] = *(const bf16x8*)&Bs[(nw + j * 16 + n15) * 64 + ks * 32 + quad * 8];
#pragma unroll
            for (int i = 0; i < 4; ++i)
#pragma unroll
                for (int j = 0; j < 4; ++j)
                    acc[i][j] = mfma16(af[i], bfr[j], acc[i][j]);
        }
    }
#pragma unroll
    for (int i = 0; i < 4; ++i) {
#pragma unroll
        for (int r = 0; r < 4; ++r) {
            int o_ = m0 + mw + i * 16 + quad * 4 + r;
            float bias = bout[o_];
            float* dst = out + ((size_t)b * 512 + o_) * L_ + n0;
#pragma unroll
            for (int j = 0; j < 4; ++j) dst[nw + j * 16 + n15] = acc[i][j][r] + bias;
        }
    }
}

// ---------- workspace layout (u16 elements) ----------
#define OFF_XBT  ((size_t)0)                            // 4*2048*512   = 4194304
#define OFF_WQKV (OFF_XBT + (size_t)B_ * L_ * 512)      // 1536*512     =  786432
#define OFF_WOUT (OFF_WQKV + (size_t)1536 * 512)        // 512*512      =  262144
#define OFF_QKV  (OFF_WOUT + (size_t)512 * 512)         // 3*4*8*2048*64= 12582912
#define OFF_O2   (OFF_QKV + (size_t)3 * B_ * 8 * L_ * 64)  // 4*2048*512

extern "C" void kernel_launch(void* const* d_in, const int* in_sizes, int n_in,
                              void* d_out, int out_size, void* d_ws, size_t ws_size,
                              hipStream_t stream) {
    (void)in_sizes; (void)n_in; (void)out_size; (void)ws_size;
    const float* x    = (const float*)d_in[0];
    const float* wqkv = (const float*)d_in[1];
    const float* wout = (const float*)d_in[2];
    const float* bout = (const float*)d_in[3];
    float* out = (float*)d_out;
    u16* ws = (u16*)d_ws;
    u16* xbt   = ws + OFF_XBT;
    u16* wqkvb = ws + OFF_WQKV;
    u16* woutb = ws + OFF_WOUT;
    u16* qkv   = ws + OFF_QKV;
    u16* o2    = ws + OFF_O2;

    convert_f32_bf16<<<768, 256, 0, stream>>>(wqkv, wqkvb, 1536 * 512);
    convert_f32_bf16<<<256, 256, 0, stream>>>(wout, woutb, 512 * 512);
    transpose_x<<<dim3(32, 8, 4), 256, 0, stream>>>(x, xbt);
    qkv_gemm<<<dim3(16, 12, 4), 256, 0, stream>>>(xbt, wqkvb, qkv);
    attn_kernel<<<dim3(16, 32), 256, 0, stream>>>(qkv, o2);
    out_gemm<<<dim3(16, 4, 4), 256, 0, stream>>>(woutb, o2, bout, out);
}